// Round 19
// baseline (144.754 us; speedup 1.0000x reference)
//
#include <hip/hip_runtime.h>

#define NB 8
#define NT 1024
#define NE 128
#define NH 8
#define NS 16

// Workspace layout (floats). Q/Kc/Vc/Y are each B*H*T*S = 1048576 floats (4 MB).
// Kc/Vc hold mask-COMPACTED keys/values (first vcount[b] rows valid per bh).
#define WS_Q 0
#define WS_KC 1048576
#define WS_VC 2097152
#define WS_Y 3145728
#define WS_VCNT 4194304

#define WT_PITCH 132  // multiple of 4 -> every row 16B-aligned for float4 LDS reads

typedef float v2f __attribute__((ext_vector_type(2)));

static __device__ __forceinline__ v2f vlo(const float4 v) { return v2f{v.x, v.y}; }
static __device__ __forceinline__ v2f vhi(const float4 v) { return v2f{v.z, v.w}; }
static __device__ __forceinline__ v2f pfma(v2f a, v2f b, v2f c) {
  return __builtin_elementwise_fma(a, b, c);  // v_pk_fma_f32 on gfx950
}

// fast 2^x: v_exp_f32 directly (avoids glibc __exp2f macro collision)
static __device__ __forceinline__ float fexp2(float x) {
  return __builtin_amdgcn_exp2f(x);
}

// packed fma4: 2 v_pk_fma_f32 instead of 4 v_fma_f32
static __device__ __forceinline__ void fma4(float4& acc, float s, const float4 v) {
  v2f lo = pfma(v2f{s, s}, vlo(v), vlo(acc));
  v2f hi = pfma(v2f{s, s}, vhi(v), vhi(acc));
  acc.x = lo.x; acc.y = lo.y; acc.z = hi.x; acc.w = hi.y;
}

// Packed-FP32 dot of two 16-float vectors.
static __device__ __forceinline__ float dot16p(const float4 q0, const float4 q1,
                                               const float4 q2, const float4 q3,
                                               const float4 k0, const float4 k1,
                                               const float4 k2, const float4 k3) {
  v2f a = vlo(q0) * vlo(k0);
  v2f b = vhi(q0) * vhi(k0);
  a = pfma(vlo(q1), vlo(k1), a);
  b = pfma(vhi(q1), vhi(k1), b);
  a = pfma(vlo(q2), vlo(k2), a);
  b = pfma(vhi(q2), vhi(k2), b);
  a = pfma(vlo(q3), vlo(k3), a);
  b = pfma(vhi(q3), vhi(k3), b);
  v2f c = a + b;
  return c.x + c.y;
}

// ---------------- Kernel A: QKV projection + in-block mask compaction ----
// grid = 1024, 256 thr. block -> (h = blk&7, rowgroup = blk>>3 of 64 rows).
// Writes K/V COMPACTED into Kc/Vc[bh][pos][16] (mask prefix computed
// in-block); Q uncompacted, scale folds log2(e) for exp2 softmax.
__global__ __launch_bounds__(256) void qkv_kernel(
    const float* __restrict__ x, const int* __restrict__ masks,
    const float* __restrict__ Wq, const float* __restrict__ Wk,
    const float* __restrict__ Wv, float* __restrict__ Q,
    float* __restrict__ Kc, float* __restrict__ Vc, int* __restrict__ vcount) {
  __shared__ __align__(16) float xs[64 * 20];  // 5120 B, pitch 20
  __shared__ int posl[64];
  const int tid = threadIdx.x;
  const int h = blockIdx.x & 7;
  const int rg = blockIdx.x >> 3;  // 0..127
  const int b = rg >> 4;
  const int bt = (rg & 15) << 6;  // batch-local row base
  {
    const int sr = tid >> 2, sq = tid & 3;
    float4 xv =
        *(const float4*)(x + (size_t)(b * NT + bt + sr) * 128 + h * 16 + sq * 4);
    *(float4*)(xs + sr * 20 + sq * 4) = xv;
  }
  if (tid < 64) {
    int cnt = 0;
    for (int c = 0; c < bt; c += 64)
      cnt += __popcll(__ballot(masks[b * NT + c + tid] != 0));
    int v = masks[b * NT + bt + tid] != 0;
    unsigned long long bal = __ballot(v);
    posl[tid] = v ? (cnt + __popcll(bal & ((1ull << tid) - 1ull))) : -1;
    if (bt == NT - 64 && tid == 0) vcount[b] = cnt + __popcll(bal);
  }
  const int d = tid & 15;
  const int r = (tid >> 4) << 2;
  const float4* wq4 = (const float4*)(Wq + d * 16);
  const float4 wq0 = wq4[0], wq1 = wq4[1], wq2 = wq4[2], wq3 = wq4[3];
  const float4* wk4 = (const float4*)(Wk + d * 16);
  const float4 wk0 = wk4[0], wk1 = wk4[1], wk2 = wk4[2], wk3 = wk4[3];
  const float4* wv4 = (const float4*)(Wv + d * 16);
  const float4 wv0 = wv4[0], wv1 = wv4[1], wv2 = wv4[2], wv3 = wv4[3];
  // log2(e) / sqrt(128): attn computes p = exp2(q.k) = exp(q.k/sqrt(E))
  const float invs = 0.12751744448143132f;
  __syncthreads();
#pragma unroll
  for (int i = 0; i < 4; i++) {
    const int row = r + i;
    const float4* xp = (const float4*)(xs + row * 20);
    const float4 x0 = xp[0], x1 = xp[1], x2 = xp[2], x3 = xp[3];
    float aq = dot16p(x0, x1, x2, x3, wq0, wq1, wq2, wq3);
    float ak = dot16p(x0, x1, x2, x3, wk0, wk1, wk2, wk3);
    float av = dot16p(x0, x1, x2, x3, wv0, wv1, wv2, wv3);
    const int t = bt + row;
    Q[((size_t)(b * NH + h) * NT + t) * NS + d] = aq * invs;
    const int pp = posl[row];
    if (pp >= 0) {
      size_t oc = ((size_t)(b * NH + h) * NT + pp) * NS + d;
      Kc[oc] = ak;
      Vc[oc] = av;
    }
  }
}

// ---------------- Kernel B: per-wave-staged, barrier-free attention ------
// Rounds 2/17/18 refute the TLP route: with block-wide staging, all waves
// issue their 32-read DS bursts in LOCKSTEP after each barrier; the CU's
// single LDS pipe round-robins the bursts, keeping waves phase-aligned ->
// wall = VALU + DS summed (44-48us), never max'd. Round-19 decouples the
// waves: each wave stages ITS OWN 4-row key-units (u == s mod 8) through a
// PRIVATE 1KB LDS slot (global -> regs, prefetched 1 unit ahead ->
// ds_write -> broadcast ds_read back). A wave reads only what it wrote ->
// ZERO main-loop barriers, waves drift freely, DS bursts interleave with
// other waves' pfmas. DS instr count unchanged (+1 write/unit), VALU +5%.
// Carried: r14 geometry (grid = 4 qgroups x 64 bh = 256 blocks, 512 thr,
// 4 queries/thread); Kc/Vc pre-compacted; fixed m=0 softmax w/ exp2
// (validated r10/r12/r14); fully-unrolled epilogue (r12 rule), one barrier
// before om reuse.
__global__ __launch_bounds__(512, 2) void attn_kernel(
    const float* __restrict__ Q, const float* __restrict__ Kc,
    const float* __restrict__ Vc, const int* __restrict__ masks,
    const int* __restrict__ vcount, float* __restrict__ Y) {
  // smem: [0..1023] per-wave K slots ([8 waves][2 buf][4 rows][16]),
  //       [1024..2047] per-wave V slots, epilogue om [8][64][20] aliases all.
  __shared__ __align__(16) float smem[10240];  // 40960 B
  const int tid = threadIdx.x;
  const int lane = tid & 63;
  const int s = tid >> 6;  // wave 0..7
  const int bh = blockIdx.x & 63;
  const int qg = blockIdx.x >> 6;  // 0..3
  const int b = bh >> 3, h = bh & 7;
  const int tbase = qg << 8;  // 256 queries per block
  const int nv = vcount[b];

  float4 q[4][4];
#pragma unroll
  for (int qq = 0; qq < 4; qq++) {
    const float4* qg4 =
        (const float4*)(Q + ((size_t)bh * NT + tbase + (qq << 6) + lane) * NS);
    q[qq][0] = qg4[0]; q[qq][1] = qg4[1]; q[qq][2] = qg4[2]; q[qq][3] = qg4[3];
  }
  v2f o[4][8];
  float l[4];
#pragma unroll
  for (int qq = 0; qq < 4; qq++) {
    l[qq] = 0.f;
#pragma unroll
    for (int k = 0; k < 8; k++) o[qq][k] = v2f{0.f, 0.f};
  }

  // per-lane staging role: lanes 0-31 carry K, 32-63 carry V; within a
  // half: row r4 = (lane>>3)&3, part pt = lane&7 (8B of the 64B row).
  const int halfv = lane >> 5;
  const int r4 = (lane >> 3) & 3;
  const int pt = lane & 7;
  const float* __restrict__ srcKV = halfv ? Vc : Kc;
  float* stg = smem + halfv * 1024 + s * 128;  // [2 buf][64]
  const float* Kr0 = smem + s * 128;
  const float* Vr0 = smem + 1024 + s * 128;
  const size_t rowbase = (size_t)bh * NT;
  const int nu = (nv + 3) >> 2;  // 4-row units; wave s owns u == s (mod 8)

  int u = s;
  v2f rv = {0.f, 0.f};
  if (u < nu) {
    const int j = (u << 2) + r4;
    if (j < nv) rv = *(const v2f*)(srcKV + (rowbase + j) * NS + (pt << 1));
  }
  int buf = 0;
#pragma unroll 2
  for (; u < nu; u += 8) {
    *(v2f*)(stg + (buf << 6) + (r4 << 4) + (pt << 1)) = rv;  // own slot
    {  // prefetch next unit (global latency hides under this unit's compute)
      const int un = u + 8;
      rv = v2f{0.f, 0.f};
      if (un < nu) {
        const int j = (un << 2) + r4;
        if (j < nv) rv = *(const v2f*)(srcKV + (rowbase + j) * NS + (pt << 1));
      }
    }
    const float* Kr = Kr0 + (buf << 6);
    const float* Vr = Vr0 + (buf << 6);
    const int j0 = u << 2;
    float sc[4][4];
#pragma unroll
    for (int i = 0; i < 4; i++) {
      const float4* kr = (const float4*)(Kr + i * 16);
      const float4 k0v = kr[0], k1v = kr[1], k2v = kr[2], k3v = kr[3];
#pragma unroll
      for (int qq = 0; qq < 4; qq++)
        sc[qq][i] =
            dot16p(q[qq][0], q[qq][1], q[qq][2], q[qq][3], k0v, k1v, k2v, k3v);
    }
#pragma unroll
    for (int i = 0; i < 4; i++)
      if (j0 + i >= nv) {
        sc[0][i] = -1e30f; sc[1][i] = -1e30f;
        sc[2][i] = -1e30f; sc[3][i] = -1e30f;
      }
    float p[4][4];
#pragma unroll
    for (int qq = 0; qq < 4; qq++) {
      p[qq][0] = fexp2(sc[qq][0]);
      p[qq][1] = fexp2(sc[qq][1]);
      p[qq][2] = fexp2(sc[qq][2]);
      p[qq][3] = fexp2(sc[qq][3]);
      l[qq] += (p[qq][0] + p[qq][1]) + (p[qq][2] + p[qq][3]);
    }
#pragma unroll
    for (int i = 0; i < 4; i++) {
      const float4* vr = (const float4*)(Vr + i * 16);
      const float4 v0 = vr[0], v1 = vr[1], v2 = vr[2], v3 = vr[3];
#pragma unroll
      for (int qq = 0; qq < 4; qq++) {
        const v2f pq = {p[qq][i], p[qq][i]};
        o[qq][0] = pfma(pq, vlo(v0), o[qq][0]);
        o[qq][1] = pfma(pq, vhi(v0), o[qq][1]);
        o[qq][2] = pfma(pq, vlo(v1), o[qq][2]);
        o[qq][3] = pfma(pq, vhi(v1), o[qq][3]);
        o[qq][4] = pfma(pq, vlo(v2), o[qq][4]);
        o[qq][5] = pfma(pq, vhi(v2), o[qq][5]);
        o[qq][6] = pfma(pq, vlo(v3), o[qq][6]);
        o[qq][7] = pfma(pq, vhi(v3), o[qq][7]);
      }
    }
    buf ^= 1;
  }

  // ---- epilogue: 4 FULLY-UNROLLED phases; fixed-m plain-sum merge ----
  // om [8][64][20] = 40960 B aliases the stage slots -> barrier first.
  float* om = smem;
  const int q8 = tid >> 3;  // 0..63
  const int sub = tid & 7;  // 0..7
#pragma unroll
  for (int ph = 0; ph < 4; ph++) {
    __syncthreads();  // stage slots / previous phase reads done
    {
      float* pa = om + (s * 64 + lane) * 20;
#pragma unroll
      for (int k = 0; k < 8; k++) *(v2f*)(pa + k * 2) = o[ph][k];
      pa[16] = l[ph];
    }
    __syncthreads();
    {
      float L = 0.f;
      v2f y = {0.f, 0.f};
#pragma unroll
      for (int ss = 0; ss < 8; ss++) {
        const float* pp = om + (ss * 64 + q8) * 20;
        L += pp[16];
        y += *(const v2f*)(pp + sub * 2);
      }
      const int tq = tbase + (ph << 6) + q8;
      const int qm = masks[b * NT + tq];
      const float inv = (qm != 0 && L > 0.f) ? (1.0f / L) : 0.f;
      y *= v2f{inv, inv};
      *(v2f*)(Y + ((size_t)b * NT + tq) * NE + h * NS + sub * 2) = y;
    }
  }
}

// ---------------- Kernel C: out = Y @ Wu^T + bu --------------------------
// grid = B*T/16 = 512 blocks, 256 threads. 16 rows/block. attn writes ALL
// query rows of Y (masked -> 0 via inv=0), so no mask handling needed here.
__global__ __launch_bounds__(256) void proj_kernel(
    const float* __restrict__ Y, const float* __restrict__ Wu,
    const float* __restrict__ bu, float* __restrict__ out) {
  __shared__ __align__(16) float Wt[64 * WT_PITCH];  // 33792 B
  __shared__ __align__(16) float Yt[16 * 128];       // 8192 B
  const int tid = threadIdx.x;
  const int r0 = blockIdx.x * 16;
  const float4* yg = (const float4*)(Y + (size_t)r0 * 128);
  float4* yt4 = (float4*)Yt;
  yt4[tid] = yg[tid];
  yt4[tid + 256] = yg[tid + 256];
  const int c0 = (tid & 31) << 2;
  const int rg = (tid >> 5) & 3;
  const int eh = tid >> 7;  // 0 or 1
  float4 acc0 = {0, 0, 0, 0}, acc1 = {0, 0, 0, 0}, acc2 = {0, 0, 0, 0},
         acc3 = {0, 0, 0, 0};
  for (int e0 = 0; e0 < 128; e0 += 64) {
    __syncthreads();  // guards Yt staging (iter 0) and Wt reuse (iter 1)
#pragma unroll
    for (int p = 0; p < 8; p++) {
      int idx = tid + p * 256;
      int c = idx >> 4;
      int es = (idx & 15) << 2;
      float4 w = *(const float4*)(Wu + c * 128 + e0 + es);
      Wt[(es + 0) * WT_PITCH + c] = w.x;
      Wt[(es + 1) * WT_PITCH + c] = w.y;
      Wt[(es + 2) * WT_PITCH + c] = w.z;
      Wt[(es + 3) * WT_PITCH + c] = w.w;
    }
    __syncthreads();
    const int eb = eh << 5;  // this thread's e-half within the 64-chunk
    const float* y0 = Yt + (rg * 4 + 0) * 128 + e0 + eb;
    const float* y1 = Yt + (rg * 4 + 1) * 128 + e0 + eb;
    const float* y2 = Yt + (rg * 4 + 2) * 128 + e0 + eb;
    const float* y3 = Yt + (rg * 4 + 3) * 128 + e0 + eb;
#pragma unroll 4
    for (int e = 0; e < 32; e += 4) {
      const float* wb = Wt + (eb + e) * WT_PITCH + c0;
      float4 w0 = *(const float4*)(wb + 0 * WT_PITCH);
      float4 w1 = *(const float4*)(wb + 1 * WT_PITCH);
      float4 w2 = *(const float4*)(wb + 2 * WT_PITCH);
      float4 w3 = *(const float4*)(wb + 3 * WT_PITCH);
      float4 ya = *(const float4*)(y0 + e);
      float4 yb = *(const float4*)(y1 + e);
      float4 yc = *(const float4*)(y2 + e);
      float4 yd = *(const float4*)(y3 + e);
      fma4(acc0, ya.x, w0); fma4(acc0, ya.y, w1); fma4(acc0, ya.z, w2); fma4(acc0, ya.w, w3);
      fma4(acc1, yb.x, w0); fma4(acc1, yb.y, w1); fma4(acc1, yb.z, w2); fma4(acc1, yb.w, w3);
      fma4(acc2, yc.x, w0); fma4(acc2, yc.y, w1); fma4(acc2, yc.z, w2); fma4(acc2, yc.w, w3);
      fma4(acc3, yd.x, w0); fma4(acc3, yd.y, w1); fma4(acc3, yd.z, w2); fma4(acc3, yd.w, w3);
    }
  }
  // combine e-halves through LDS (Wt dead; pitch 20 to spread banks)
  __syncthreads();
  if (eh == 1) {
    float* p = Wt + (tid & 127) * 20;
    *(float4*)(p + 0) = acc0; *(float4*)(p + 4) = acc1;
    *(float4*)(p + 8) = acc2; *(float4*)(p + 12) = acc3;
  }
  __syncthreads();
  if (eh == 0) {
    const float* p = Wt + tid * 20;
    float4 b4 = *(const float4*)(bu + c0);
    float4 q0 = *(const float4*)(p + 0);
    float4 q1 = *(const float4*)(p + 4);
    float4 q2 = *(const float4*)(p + 8);
    float4 q3 = *(const float4*)(p + 12);
    acc0.x += q0.x + b4.x; acc0.y += q0.y + b4.y; acc0.z += q0.z + b4.z; acc0.w += q0.w + b4.w;
    acc1.x += q1.x + b4.x; acc1.y += q1.y + b4.y; acc1.z += q1.z + b4.z; acc1.w += q1.w + b4.w;
    acc2.x += q2.x + b4.x; acc2.y += q2.y + b4.y; acc2.z += q2.z + b4.z; acc2.w += q2.w + b4.w;
    acc3.x += q3.x + b4.x; acc3.y += q3.y + b4.y; acc3.z += q3.z + b4.z; acc3.w += q3.w + b4.w;
    *(float4*)(out + (size_t)(r0 + rg * 4 + 0) * 128 + c0) = acc0;
    *(float4*)(out + (size_t)(r0 + rg * 4 + 1) * 128 + c0) = acc1;
    *(float4*)(out + (size_t)(r0 + rg * 4 + 2) * 128 + c0) = acc2;
    *(float4*)(out + (size_t)(r0 + rg * 4 + 3) * 128 + c0) = acc3;
  }
}

extern "C" void kernel_launch(void* const* d_in, const int* in_sizes, int n_in,
                              void* d_out, int out_size, void* d_ws,
                              size_t ws_size, hipStream_t stream) {
  const float* x = (const float*)d_in[0];
  const int* masks = (const int*)d_in[1];
  const float* Wq = (const float*)d_in[2];
  const float* Wk = (const float*)d_in[3];
  const float* Wv = (const float*)d_in[4];
  const float* Wu = (const float*)d_in[5];
  const float* bu = (const float*)d_in[6];
  float* out = (float*)d_out;

  float* ws = (float*)d_ws;
  float* Q = ws + WS_Q;
  float* Kc = ws + WS_KC;
  float* Vc = ws + WS_VC;
  float* Y = ws + WS_Y;
  int* vcount = (int*)(ws + WS_VCNT);

  qkv_kernel<<<1024, 256, 0, stream>>>(x, masks, Wq, Wk, Wv, Q, Kc, Vc,
                                       vcount);
  // grid = 4 query-groups (256 q) x 64 bh = 256 blocks (1/CU), 512 thr
  attn_kernel<<<4 * NB * NH, 512, 0, stream>>>(Q, Kc, Vc, masks, vcount, Y);
  proj_kernel<<<NB * NT / 16, 256, 0, stream>>>(Y, Wu, bu, out);
}